// Round 5
// baseline (218.296 us; speedup 1.0000x reference)
//
#include <hip/hip_runtime.h>

// ScalarDistanceDeepSet: B=32, N=256, pairs P=32640 (upper tri, k=1)
// phi: s -> relu(s*W1+b1)[64] -> relu(.@W2+b2)[128], masked sum over pairs
// rho: pooled[128] -> 256 -> 128 -> 64
//
// g_e(s) is piecewise-linear in s with 64 shared breakpoints. Tables
// alpha/beta[seg][e] make per-(pair,channel) work 1 FMA + 1 max. EXACT.
//
// R11: accounting across R0/R7/R9/R10 shows ~80us/iter is harness fill
// drain; our kernels are ~60us with phi ~35-40. R10's parity split made
// phi WORSE (54us: 4x table staging + 4x row loads > balance gain) and
// showed VGPR_Count~12 is this loop's NORMAL lean codegen (not spill
// collapse); R8/R9's 133us was the batched interior itself (bad twice).
// R11 therefore = R0's kernels verbatim (proven phi inner loop, proven
// build_tables) + R9's PROVEN-EXACT rho fusion tail (per-batch counter;
// last block runs the MLP reading weights direct from global). Removes
// the rho kernel + one launch gap. LDS 33.3->35.3KB, still 4 blocks/CU.

#define NB 32
#define NN 256
#define PHI2 128
#define SEGS 65

// ---------------- Kernel A: build tables (+ zero pooled & counters) -------
// grid: 65 blocks (one per segment), 128 threads (one per output channel e)
// table2[h][seg][l] = {alpha, beta} for channel h*64+l
__global__ __launch_bounds__(128) void build_tables(
    const float* __restrict__ W1, const float* __restrict__ b1,
    const float* __restrict__ W2, const float* __restrict__ b2,
    float2* __restrict__ table2,   // [2][SEGS][64]
    float* __restrict__ tsort, float* __restrict__ pooled,
    int* __restrict__ cnt) {
  __shared__ float w2_s[64 * PHI2];   // 32 KB
  __shared__ float t_s[64], w1_s[64], b1_s[64];
  __shared__ int cat_s[64], rank_s[64];
  const int tid = threadIdx.x;
  const int seg = blockIdx.x;
  const float4* W2v = (const float4*)W2;
  float4* w2v = (float4*)w2_s;
  for (int i = tid; i < 64 * PHI2 / 4; i += 128) w2v[i] = W2v[i];
  if (tid < 64) {
    float w = W1[tid], bb = b1[tid];
    w1_s[tid] = w; b1_s[tid] = bb;
    int cat; float t;
    if (w > 0.f)      { cat = 0; t = -bb / w; }   // active for s > t
    else if (w < 0.f) { cat = 1; t = -bb / w; }   // active for s < t
    else              { cat = (bb > 0.f) ? 2 : 3; t = 0.f; } // always/never
    t_s[tid] = t; cat_s[tid] = cat;
  }
  __syncthreads();
  if (tid < 64) {
    float t = t_s[tid]; int r = 0;
    for (int k = 0; k < 64; ++k) {
      float tk = t_s[k];
      r += (tk < t) || (tk == t && k < tid);   // stable rank
    }
    rank_s[tid] = r;
    if (seg == 0) tsort[r] = t;
  }
  __syncthreads();
  // channel e = tid. seg(s) = #breakpoints strictly < s.
  float a = 0.f, bsum = b2[tid];
#pragma unroll 8
  for (int j = 0; j < 64; ++j) {
    int cat = cat_s[j], r = rank_s[j];
    bool act = (cat == 0) ? (seg > r) : (cat == 1) ? (seg <= r) : (cat == 2);
    float w2 = w2_s[j * PHI2 + tid];
    float m = act ? 1.f : 0.f;
    a    = fmaf(m * w1_s[j], w2, a);
    bsum = fmaf(m * b1_s[j], w2, bsum);
  }
  const int h = tid >> 6, l = tid & 63;
  table2[((h * SEGS) + seg) * 64 + l] = make_float2(a, bsum);
  if (seg == 0) {
    for (int i = tid; i < NB * PHI2; i += 128) pooled[i] = 0.f;
    if (tid < NB) cnt[tid] = 0;
  }
}

// One (pair, channel) visit: broadcast s from lane L (uniform), segment via
// ballot over register-held sorted breakpoints, one contiguous ds_read_b64.
__device__ __forceinline__ void visit(float comp, int L, float tv, int lane,
                                      const float2* ab_s, float& acc) {
  float s = __int_as_float(__builtin_amdgcn_readlane(__float_as_int(comp), L));
  int pos = (int)__popcll(__ballot(tv < s));
  float2 p = ab_s[pos * 64 + lane];
  acc += fmaxf(fmaf(p.x, s, p.y), 0.f);
}

// Dynamic-component visit for ragged row edges (<=6 per row).
__device__ __forceinline__ void visit_dyn(const float4& f4, int j, float tv,
                                          int lane, const float2* ab_s,
                                          float& acc) {
  int c = j & 3;
  float comp = (c == 0) ? f4.x : (c == 1) ? f4.y : (c == 2) ? f4.z : f4.w;
  visit(comp, j >> 2, tv, lane, ab_s, acc);
}

// Process one row: f4 holds the full 256-float row across the wave
// (lane holds cols 4*lane..4*lane+3). Valid cols j in [i0+1, len-1].
__device__ __forceinline__ void do_row(const float4& f4, int i0, int len,
                                       float tv, int lane,
                                       const float2* ab_s, float& acc) {
  const int jlo = i0 + 1, jhi = len - 1;   // inclusive; jhi >= jlo guaranteed
  const int fullLo = (jlo + 3) >> 2;       // first fully-valid 4-group
  const int fullHi = (jhi >= 3) ? ((jhi - 3) >> 2) : -1;  // last fully-valid
  if (fullLo > fullHi) {
    for (int j = jlo; j <= jhi; ++j) visit_dyn(f4, j, tv, lane, ab_s, acc);
    return;
  }
  // low ragged edge
  for (int j = jlo; j < fullLo * 4; ++j) visit_dyn(f4, j, tv, lane, ab_s, acc);
  // interior full groups: uniform L in SGPR, static components
#pragma unroll 4
  for (int L = fullLo; L <= fullHi; ++L) {
    visit(f4.x, L, tv, lane, ab_s, acc);
    visit(f4.y, L, tv, lane, ab_s, acc);
    visit(f4.z, L, tv, lane, ab_s, acc);
    visit(f4.w, L, tv, lane, ab_s, acc);
  }
  // high ragged edge
  for (int j = fullHi * 4 + 4; j <= jhi; ++j)
    visit_dyn(f4, j, tv, lane, ab_s, acc);
}

// ---------------- Kernel B: phi + masked pooling + fused rho --------------
// grid: (16 row-chunks, 2 halves, 32 batches) x 512 threads (8 waves).
// Wave w owns row r = chunk*8+w (0..127) and its mirror 254-r (balanced).
// Last participating block of batch b (per-batch device counter over BOTH
// halves) runs the rho MLP for that batch, weights direct from global.
__global__ __launch_bounds__(512, 8) void phi_pool_rho(
    const float* __restrict__ dm, const int* __restrict__ lengths,
    const float2* __restrict__ table2, const float* __restrict__ tsort,
    float* __restrict__ pooled, int* __restrict__ cnt,
    const float* __restrict__ W3, const float* __restrict__ b3,
    const float* __restrict__ W4, const float* __restrict__ b4,
    const float* __restrict__ W5, const float* __restrict__ b5,
    float* __restrict__ out) {
  __shared__ float2 ab_s[SEGS * 64];   // 33,280 B
  __shared__ float p_s[128], r1_s[256], r2_s[128];
  __shared__ int lastflag;
  const int chunk = blockIdx.x;   // 0..15
  const int h     = blockIdx.y;   // channel half
  const int b     = blockIdx.z;   // batch
  const int tid = threadIdx.x;
  const int lane = tid & 63, w = tid >> 6;

  const int len = lengths[b];
  // block-uniform early exit: no primary row (8c) and no mirror row (247-8c)
  if (8 * chunk > len - 2 && 247 - 8 * chunk > len - 2) return;

  const float2* tg = table2 + h * SEGS * 64;
  for (int i = tid; i < SEGS * 64; i += 512) ab_s[i] = tg[i];
  __syncthreads();

  const float tv = tsort[lane];      // breakpoint in register, one per lane
  const float* dmb = dm + (size_t)b * (NN * NN);
  float acc = 0.f;

  const int rA = chunk * 8 + w;      // 0..127
  const int rB = 254 - rA;           // 127..254
  // issue both full-row loads up-front (always address-valid)
  const float4 fA = ((const float4*)(dmb + rA * NN))[lane];
  const float4 fB = ((const float4*)(dmb + rB * NN))[lane];
  if (rA <= len - 2) do_row(fA, rA, len, tv, lane, ab_s, acc);
  if (rB != rA && rB <= len - 2) do_row(fB, rB, len, tv, lane, ab_s, acc);

  atomicAdd(&pooled[b * PHI2 + h * 64 + lane], acc);

  // release: per-thread fence, then barrier (all block atomics reach the
  // device coherence point before the counter signal).
  __threadfence();
  __syncthreads();
  if (tid == 0) {
    int npart = 0;
    for (int c = 0; c < 16; ++c)
      npart += (8 * c <= len - 2) || (247 - 8 * c <= len - 2);
    npart *= 2;   // both channel halves
    lastflag = (atomicAdd(&cnt[b], 1) == npart - 1) ? 1 : 0;
  }
  __syncthreads();
  if (!lastflag) return;

  // ---- rho for batch b (runs once, in the last-arriving block) ----
  // acquire-read pooled via atomic RMW (same coherence point as writers).
  if (tid < 128) p_s[tid] = atomicAdd(&pooled[b * PHI2 + tid], 0.0f);
  __syncthreads();
  if (tid < 256) {
    float acc2 = b3[tid];
#pragma unroll 8
    for (int k = 0; k < 128; ++k) acc2 = fmaf(p_s[k], W3[k * 256 + tid], acc2);
    r1_s[tid] = fmaxf(acc2, 0.f);
  }
  __syncthreads();
  if (tid < 128) {
    float acc2 = b4[tid];
#pragma unroll 8
    for (int k = 0; k < 256; ++k) acc2 = fmaf(r1_s[k], W4[k * 128 + tid], acc2);
    r2_s[tid] = fmaxf(acc2, 0.f);
  }
  __syncthreads();
  if (tid < 64) {
    float acc2 = b5[tid];
#pragma unroll 8
    for (int k = 0; k < 128; ++k) acc2 = fmaf(r2_s[k], W5[k * 64 + tid], acc2);
    out[b * 64 + tid] = acc2;
  }
}

extern "C" void kernel_launch(void* const* d_in, const int* in_sizes, int n_in,
                              void* d_out, int out_size, void* d_ws, size_t ws_size,
                              hipStream_t stream) {
  const float* dm      = (const float*)d_in[0];
  const int*   lengths = (const int*)d_in[1];
  const float* W1 = (const float*)d_in[2];
  const float* b1 = (const float*)d_in[3];
  const float* W2 = (const float*)d_in[4];
  const float* b2 = (const float*)d_in[5];
  const float* W3 = (const float*)d_in[6];
  const float* b3 = (const float*)d_in[7];
  const float* W4 = (const float*)d_in[8];
  const float* b4 = (const float*)d_in[9];
  const float* W5 = (const float*)d_in[10];
  const float* b5 = (const float*)d_in[11];

  float* ws = (float*)d_ws;
  float2* table2 = (float2*)ws;          // 2*65*64 float2 = 16640 floats
  float* tsort   = ws + 16640;           // 64
  float* pooled  = ws + 16704;           // 32*128 = 4096
  int*   cnt     = (int*)(ws + 20800);   // 32

  build_tables<<<SEGS, 128, 0, stream>>>(W1, b1, W2, b2, table2, tsort,
                                         pooled, cnt);
  phi_pool_rho<<<dim3(16, 2, NB), 512, 0, stream>>>(
      dm, lengths, table2, tsort, pooled, cnt,
      W3, b3, W4, b4, W5, b5, (float*)d_out);
}

// Round 6
// 139.692 us; speedup vs baseline: 1.5627x; 1.5627x over previous
//
#include <hip/hip_runtime.h>

// ScalarDistanceDeepSet: B=32, N=256, pairs P=32640 (upper tri, k=1)
// phi: s -> relu(s*W1+b1)[64] -> relu(.@W2+b2)[128], masked sum over pairs
// rho: pooled[128] -> 256 -> 128 -> 64
//
// g_e(s) is piecewise-linear in s with 64 shared breakpoints. Tables
// alpha/beta[seg][e] make per-(pair,channel) work 1 FMA + 1 max. EXACT.
//
// R12: the fusion 2x2 is complete. R11 (R0 phi loop + fused rho tail) ==
// R8/R9 (batched loop + tail) == 133us, VGPR=16 -> the FUSED TAIL is the
// poison (3x phi slowdown, reproduced 3x); batching was never isolated.
// Fusion is abandoned for good. This round: R0's three-kernel structure
// VERBATIM, with one change -- do_row's interior uses the two-stage batch
// (4 broadcasts -> 4 ballots -> 4 ds_read_b64 in flight -> 4 fma/max in
// original order, EXACT) to pipeline the ~146cyc LDS latency chain that
// R10's counters showed is serialized (VALUBusy 22%, VGPR=12: zero loads
// in flight). Tests the last untested cell: batching WITHOUT fusion.

#define NB 32
#define NN 256
#define PHI2 128
#define SEGS 65

// ---------------- Kernel A: build tables ----------------
// grid: 65 blocks (one per segment), 128 threads (one per output channel e)
// table2[h][seg][l] = {alpha, beta} for channel h*64+l
__global__ __launch_bounds__(128) void build_tables(
    const float* __restrict__ W1, const float* __restrict__ b1,
    const float* __restrict__ W2, const float* __restrict__ b2,
    float2* __restrict__ table2,   // [2][SEGS][64]
    float* __restrict__ tsort, float* __restrict__ pooled) {
  __shared__ float w2_s[64 * PHI2];   // 32 KB
  __shared__ float t_s[64], w1_s[64], b1_s[64];
  __shared__ int cat_s[64], rank_s[64];
  const int tid = threadIdx.x;
  const int seg = blockIdx.x;
  const float4* W2v = (const float4*)W2;
  float4* w2v = (float4*)w2_s;
  for (int i = tid; i < 64 * PHI2 / 4; i += 128) w2v[i] = W2v[i];
  if (tid < 64) {
    float w = W1[tid], bb = b1[tid];
    w1_s[tid] = w; b1_s[tid] = bb;
    int cat; float t;
    if (w > 0.f)      { cat = 0; t = -bb / w; }   // active for s > t
    else if (w < 0.f) { cat = 1; t = -bb / w; }   // active for s < t
    else              { cat = (bb > 0.f) ? 2 : 3; t = 0.f; } // always/never
    t_s[tid] = t; cat_s[tid] = cat;
  }
  __syncthreads();
  if (tid < 64) {
    float t = t_s[tid]; int r = 0;
    for (int k = 0; k < 64; ++k) {
      float tk = t_s[k];
      r += (tk < t) || (tk == t && k < tid);   // stable rank
    }
    rank_s[tid] = r;
    if (seg == 0) tsort[r] = t;
  }
  __syncthreads();
  // channel e = tid. seg(s) = #breakpoints strictly < s.
  float a = 0.f, bsum = b2[tid];
#pragma unroll 8
  for (int j = 0; j < 64; ++j) {
    int cat = cat_s[j], r = rank_s[j];
    bool act = (cat == 0) ? (seg > r) : (cat == 1) ? (seg <= r) : (cat == 2);
    float w2 = w2_s[j * PHI2 + tid];
    float m = act ? 1.f : 0.f;
    a    = fmaf(m * w1_s[j], w2, a);
    bsum = fmaf(m * b1_s[j], w2, bsum);
  }
  const int h = tid >> 6, l = tid & 63;
  table2[((h * SEGS) + seg) * 64 + l] = make_float2(a, bsum);
  if (seg == 0) {
    for (int i = tid; i < NB * PHI2; i += 128) pooled[i] = 0.f;
  }
}

__device__ __forceinline__ float bcast(float v, int L) {
  return __int_as_float(__builtin_amdgcn_readlane(__float_as_int(v), L));
}
__device__ __forceinline__ int segof(float tv, float s) {
  return (int)__popcll(__ballot(tv < s));
}

// One (pair, channel) visit: broadcast s from lane L (uniform), segment via
// ballot over register-held sorted breakpoints, one contiguous ds_read_b64.
__device__ __forceinline__ void visit(float comp, int L, float tv, int lane,
                                      const float2* ab_s, float& acc) {
  float s = bcast(comp, L);
  float2 p = ab_s[segof(tv, s) * 64 + lane];
  acc += fmaxf(fmaf(p.x, s, p.y), 0.f);
}

// Dynamic-component visit for ragged row edges (<=6 per row).
__device__ __forceinline__ void visit_dyn(const float4& f4, int j, float tv,
                                          int lane, const float2* ab_s,
                                          float& acc) {
  int c = j & 3;
  float comp = (c == 0) ? f4.x : (c == 1) ? f4.y : (c == 2) ? f4.z : f4.w;
  visit(comp, j >> 2, tv, lane, ab_s, acc);
}

// Process one row: f4 holds the full 256-float row across the wave
// (lane holds cols 4*lane..4*lane+3). Valid cols j in [i0+1, len-1].
// Interior groups are two-stage batched: 4 broadcasts/ballots, then 4
// ds_read_b64 issued together (in flight), then 4 fma/max in the ORIGINAL
// sequential order -> bitwise-identical accumulation.
__device__ __forceinline__ void do_row(const float4& f4, int i0, int len,
                                       float tv, int lane,
                                       const float2* ab_s, float& acc) {
  const int jlo = i0 + 1, jhi = len - 1;   // inclusive; jhi >= jlo guaranteed
  const int fullLo = (jlo + 3) >> 2;       // first fully-valid 4-group
  const int fullHi = (jhi >= 3) ? ((jhi - 3) >> 2) : -1;  // last fully-valid
  if (fullLo > fullHi) {
    for (int j = jlo; j <= jhi; ++j) visit_dyn(f4, j, tv, lane, ab_s, acc);
    return;
  }
  // low ragged edge
  for (int j = jlo; j < fullLo * 4; ++j) visit_dyn(f4, j, tv, lane, ab_s, acc);
  // interior full groups: uniform L in SGPR, static components, batched
#pragma unroll 2
  for (int L = fullLo; L <= fullHi; ++L) {
    float s0 = bcast(f4.x, L), s1 = bcast(f4.y, L);
    float s2 = bcast(f4.z, L), s3 = bcast(f4.w, L);
    int p0 = segof(tv, s0), p1 = segof(tv, s1);
    int p2 = segof(tv, s2), p3 = segof(tv, s3);
    float2 q0 = ab_s[p0 * 64 + lane];
    float2 q1 = ab_s[p1 * 64 + lane];
    float2 q2 = ab_s[p2 * 64 + lane];
    float2 q3 = ab_s[p3 * 64 + lane];
    acc += fmaxf(fmaf(q0.x, s0, q0.y), 0.f);
    acc += fmaxf(fmaf(q1.x, s1, q1.y), 0.f);
    acc += fmaxf(fmaf(q2.x, s2, q2.y), 0.f);
    acc += fmaxf(fmaf(q3.x, s3, q3.y), 0.f);
  }
  // high ragged edge
  for (int j = fullHi * 4 + 4; j <= jhi; ++j)
    visit_dyn(f4, j, tv, lane, ab_s, acc);
}

// ---------------- Kernel B: phi + masked pooling ----------------
// grid: (16 row-chunks, 2 halves, 32 batches) x 512 threads (8 waves).
// Wave w owns row r = chunk*8+w (0..127) and its mirror 254-r (balanced).
__global__ __launch_bounds__(512, 8) void phi_pool(
    const float* __restrict__ dm, const int* __restrict__ lengths,
    const float2* __restrict__ table2, const float* __restrict__ tsort,
    float* __restrict__ pooled) {
  __shared__ float2 ab_s[SEGS * 64];   // 33,280 B -> 4 blocks/CU
  const int chunk = blockIdx.x;   // 0..15
  const int h     = blockIdx.y;   // channel half
  const int b     = blockIdx.z;   // batch
  const int tid = threadIdx.x;
  const int lane = tid & 63, w = tid >> 6;

  const int len = lengths[b];
  // block-uniform early exit: no primary row (8c) and no mirror row (247-8c)
  if (8 * chunk > len - 2 && 247 - 8 * chunk > len - 2) return;

  const float2* tg = table2 + h * SEGS * 64;
  for (int i = tid; i < SEGS * 64; i += 512) ab_s[i] = tg[i];
  __syncthreads();

  const float tv = tsort[lane];      // breakpoint in register, one per lane
  const float* dmb = dm + (size_t)b * (NN * NN);
  float acc = 0.f;

  const int rA = chunk * 8 + w;      // 0..127
  const int rB = 254 - rA;           // 127..254
  // issue both full-row loads up-front (always address-valid)
  const float4 fA = ((const float4*)(dmb + rA * NN))[lane];
  const float4 fB = ((const float4*)(dmb + rB * NN))[lane];
  if (rA <= len - 2) do_row(fA, rA, len, tv, lane, ab_s, acc);
  if (rB != rA && rB <= len - 2) do_row(fB, rB, len, tv, lane, ab_s, acc);

  atomicAdd(&pooled[b * PHI2 + h * 64 + lane], acc);
}

// ---------------- Kernel C: rho MLP ----------------
// grid: 32 blocks (one per batch), 256 threads. Weight layers staged
// through one reused 128 KB LDS buffer with independent float4 loads.
__global__ __launch_bounds__(256) void rho_mlp(
    const float* __restrict__ pooled,
    const float* __restrict__ W3, const float* __restrict__ b3,
    const float* __restrict__ W4, const float* __restrict__ b4,
    const float* __restrict__ W5, const float* __restrict__ b5,
    float* __restrict__ out) {
  __shared__ float w_s[128 * 256];     // 128 KB, reused per layer
  __shared__ float p_s[128], r1_s[256], r2_s[128];
  const int b = blockIdx.x, tid = threadIdx.x;
  float4* wsv = (float4*)w_s;
  {
    const float4* w3v = (const float4*)W3;
    for (int i = tid; i < 8192; i += 256) wsv[i] = w3v[i];
  }
  if (tid < 128) p_s[tid] = pooled[b * 128 + tid];
  __syncthreads();
  {
    float acc = b3[tid];
#pragma unroll 8
    for (int k = 0; k < 128; ++k) acc = fmaf(p_s[k], w_s[k * 256 + tid], acc);
    r1_s[tid] = fmaxf(acc, 0.f);
  }
  __syncthreads();
  {
    const float4* w4v = (const float4*)W4;
    for (int i = tid; i < 8192; i += 256) wsv[i] = w4v[i];
  }
  __syncthreads();
  if (tid < 128) {
    float acc = b4[tid];
#pragma unroll 8
    for (int k = 0; k < 256; ++k) acc = fmaf(r1_s[k], w_s[k * 128 + tid], acc);
    r2_s[tid] = fmaxf(acc, 0.f);
  }
  __syncthreads();
  {
    const float4* w5v = (const float4*)W5;
    for (int i = tid; i < 2048; i += 256) wsv[i] = w5v[i];
  }
  __syncthreads();
  if (tid < 64) {
    float acc = b5[tid];
#pragma unroll 8
    for (int k = 0; k < 128; ++k) acc = fmaf(r2_s[k], w_s[k * 64 + tid], acc);
    out[b * 64 + tid] = acc;
  }
}

extern "C" void kernel_launch(void* const* d_in, const int* in_sizes, int n_in,
                              void* d_out, int out_size, void* d_ws, size_t ws_size,
                              hipStream_t stream) {
  const float* dm      = (const float*)d_in[0];
  const int*   lengths = (const int*)d_in[1];
  const float* W1 = (const float*)d_in[2];
  const float* b1 = (const float*)d_in[3];
  const float* W2 = (const float*)d_in[4];
  const float* b2 = (const float*)d_in[5];
  const float* W3 = (const float*)d_in[6];
  const float* b3 = (const float*)d_in[7];
  const float* W4 = (const float*)d_in[8];
  const float* b4 = (const float*)d_in[9];
  const float* W5 = (const float*)d_in[10];
  const float* b5 = (const float*)d_in[11];

  float* ws = (float*)d_ws;
  float2* table2 = (float2*)ws;          // 2*65*64 float2 = 16640 floats
  float* tsort   = ws + 16640;           // 64
  float* pooled  = ws + 16704;           // 32*128 = 4096

  build_tables<<<SEGS, 128, 0, stream>>>(W1, b1, W2, b2, table2, tsort, pooled);
  phi_pool<<<dim3(16, 2, NB), 512, 0, stream>>>(dm, lengths, table2, tsort, pooled);
  rho_mlp<<<NB, 256, 0, stream>>>(pooled, W3, b3, W4, b4, W5, b5, (float*)d_out);
}

// Round 7
// 134.977 us; speedup vs baseline: 1.6173x; 1.0349x over previous
//
#include <hip/hip_runtime.h>

// ScalarDistanceDeepSet: B=32, N=256, pairs P=32640 (upper tri, k=1)
// phi: s -> relu(s*W1+b1)[64] -> relu(.@W2+b2)[128], masked sum over pairs
// rho: pooled[128] -> 256 -> 128 -> 64
//
// g_e(s) is piecewise-linear in s with 64 shared breakpoints. Tables
// alpha/beta[seg][e] make per-(pair,channel) work 1 FMA + 1 max. EXACT.
//
// R13: cross-round accounting (R4 rest=107 vs R5 rest=85) shows rho_mlp
// costs ~17-21us -- its 128KB LDS weight staging forces 1 block/CU (32 CUs)
// and serializes 288KB of L2->LDS traffic before 4.7 MFLOP of math. The
// R11 fused tail proved direct coalesced global weight reads are EXACT
// (absmax 0.0, same k-ascending fmaf order). R13 = R0's build_tables +
// phi_pool VERBATIM (proven codegen, phi ~32us) + rho_mlp rewritten with
// no weight staging (2KB LDS, consecutive-tid coalesced W reads, unroll-8
// keeps 8 loads in flight). Single variable vs R0. Fusion stays dead
// (it poisons phi codegen: 3x, R8/R9/R11).

#define NB 32
#define NN 256
#define PHI2 128
#define SEGS 65

// ---------------- Kernel A: build tables ----------------
// grid: 65 blocks (one per segment), 128 threads (one per output channel e)
// table2[h][seg][l] = {alpha, beta} for channel h*64+l
__global__ __launch_bounds__(128) void build_tables(
    const float* __restrict__ W1, const float* __restrict__ b1,
    const float* __restrict__ W2, const float* __restrict__ b2,
    float2* __restrict__ table2,   // [2][SEGS][64]
    float* __restrict__ tsort, float* __restrict__ pooled) {
  __shared__ float w2_s[64 * PHI2];   // 32 KB
  __shared__ float t_s[64], w1_s[64], b1_s[64];
  __shared__ int cat_s[64], rank_s[64];
  const int tid = threadIdx.x;
  const int seg = blockIdx.x;
  const float4* W2v = (const float4*)W2;
  float4* w2v = (float4*)w2_s;
  for (int i = tid; i < 64 * PHI2 / 4; i += 128) w2v[i] = W2v[i];
  if (tid < 64) {
    float w = W1[tid], bb = b1[tid];
    w1_s[tid] = w; b1_s[tid] = bb;
    int cat; float t;
    if (w > 0.f)      { cat = 0; t = -bb / w; }   // active for s > t
    else if (w < 0.f) { cat = 1; t = -bb / w; }   // active for s < t
    else              { cat = (bb > 0.f) ? 2 : 3; t = 0.f; } // always/never
    t_s[tid] = t; cat_s[tid] = cat;
  }
  __syncthreads();
  if (tid < 64) {
    float t = t_s[tid]; int r = 0;
    for (int k = 0; k < 64; ++k) {
      float tk = t_s[k];
      r += (tk < t) || (tk == t && k < tid);   // stable rank
    }
    rank_s[tid] = r;
    if (seg == 0) tsort[r] = t;
  }
  __syncthreads();
  // channel e = tid. seg(s) = #breakpoints strictly < s.
  float a = 0.f, bsum = b2[tid];
#pragma unroll 8
  for (int j = 0; j < 64; ++j) {
    int cat = cat_s[j], r = rank_s[j];
    bool act = (cat == 0) ? (seg > r) : (cat == 1) ? (seg <= r) : (cat == 2);
    float w2 = w2_s[j * PHI2 + tid];
    float m = act ? 1.f : 0.f;
    a    = fmaf(m * w1_s[j], w2, a);
    bsum = fmaf(m * b1_s[j], w2, bsum);
  }
  const int h = tid >> 6, l = tid & 63;
  table2[((h * SEGS) + seg) * 64 + l] = make_float2(a, bsum);
  if (seg == 0) {
    for (int i = tid; i < NB * PHI2; i += 128) pooled[i] = 0.f;
  }
}

// One (pair, channel) visit: broadcast s from lane L (uniform), segment via
// ballot over register-held sorted breakpoints, one contiguous ds_read_b64.
__device__ __forceinline__ void visit(float comp, int L, float tv, int lane,
                                      const float2* ab_s, float& acc) {
  float s = __int_as_float(__builtin_amdgcn_readlane(__float_as_int(comp), L));
  int pos = (int)__popcll(__ballot(tv < s));
  float2 p = ab_s[pos * 64 + lane];
  acc += fmaxf(fmaf(p.x, s, p.y), 0.f);
}

// Dynamic-component visit for ragged row edges (<=6 per row).
__device__ __forceinline__ void visit_dyn(const float4& f4, int j, float tv,
                                          int lane, const float2* ab_s,
                                          float& acc) {
  int c = j & 3;
  float comp = (c == 0) ? f4.x : (c == 1) ? f4.y : (c == 2) ? f4.z : f4.w;
  visit(comp, j >> 2, tv, lane, ab_s, acc);
}

// Process one row: f4 holds the full 256-float row across the wave
// (lane holds cols 4*lane..4*lane+3). Valid cols j in [i0+1, len-1].
__device__ __forceinline__ void do_row(const float4& f4, int i0, int len,
                                       float tv, int lane,
                                       const float2* ab_s, float& acc) {
  const int jlo = i0 + 1, jhi = len - 1;   // inclusive; jhi >= jlo guaranteed
  const int fullLo = (jlo + 3) >> 2;       // first fully-valid 4-group
  const int fullHi = (jhi >= 3) ? ((jhi - 3) >> 2) : -1;  // last fully-valid
  if (fullLo > fullHi) {
    for (int j = jlo; j <= jhi; ++j) visit_dyn(f4, j, tv, lane, ab_s, acc);
    return;
  }
  // low ragged edge
  for (int j = jlo; j < fullLo * 4; ++j) visit_dyn(f4, j, tv, lane, ab_s, acc);
  // interior full groups: uniform L in SGPR, static components
#pragma unroll 4
  for (int L = fullLo; L <= fullHi; ++L) {
    visit(f4.x, L, tv, lane, ab_s, acc);
    visit(f4.y, L, tv, lane, ab_s, acc);
    visit(f4.z, L, tv, lane, ab_s, acc);
    visit(f4.w, L, tv, lane, ab_s, acc);
  }
  // high ragged edge
  for (int j = fullHi * 4 + 4; j <= jhi; ++j)
    visit_dyn(f4, j, tv, lane, ab_s, acc);
}

// ---------------- Kernel B: phi + masked pooling ----------------
// grid: (16 row-chunks, 2 halves, 32 batches) x 512 threads (8 waves).
// Wave w owns row r = chunk*8+w (0..127) and its mirror 254-r (balanced).
__global__ __launch_bounds__(512, 8) void phi_pool(
    const float* __restrict__ dm, const int* __restrict__ lengths,
    const float2* __restrict__ table2, const float* __restrict__ tsort,
    float* __restrict__ pooled) {
  __shared__ float2 ab_s[SEGS * 64];   // 33,280 B -> 4 blocks/CU
  const int chunk = blockIdx.x;   // 0..15
  const int h     = blockIdx.y;   // channel half
  const int b     = blockIdx.z;   // batch
  const int tid = threadIdx.x;
  const int lane = tid & 63, w = tid >> 6;

  const int len = lengths[b];
  // block-uniform early exit: no primary row (8c) and no mirror row (247-8c)
  if (8 * chunk > len - 2 && 247 - 8 * chunk > len - 2) return;

  const float2* tg = table2 + h * SEGS * 64;
  for (int i = tid; i < SEGS * 64; i += 512) ab_s[i] = tg[i];
  __syncthreads();

  const float tv = tsort[lane];      // breakpoint in register, one per lane
  const float* dmb = dm + (size_t)b * (NN * NN);
  float acc = 0.f;

  const int rA = chunk * 8 + w;      // 0..127
  const int rB = 254 - rA;           // 127..254
  // issue both full-row loads up-front (always address-valid)
  const float4 fA = ((const float4*)(dmb + rA * NN))[lane];
  const float4 fB = ((const float4*)(dmb + rB * NN))[lane];
  if (rA <= len - 2) do_row(fA, rA, len, tv, lane, ab_s, acc);
  if (rB != rA && rB <= len - 2) do_row(fB, rB, len, tv, lane, ab_s, acc);

  atomicAdd(&pooled[b * PHI2 + h * 64 + lane], acc);
}

// ---------------- Kernel C: rho MLP (no weight staging) ----------------
// grid: 32 blocks (one per batch), 256 threads. Weights read directly from
// global, coalesced (consecutive tids -> consecutive addresses); unroll-8
// keeps 8 L2-hot loads in flight. Same k-ascending fmaf order as always.
// LDS: 2KB (p_s/r1_s/r2_s) -> no occupancy constraint, no staging stall.
__global__ __launch_bounds__(256) void rho_mlp(
    const float* __restrict__ pooled,
    const float* __restrict__ W3, const float* __restrict__ b3,
    const float* __restrict__ W4, const float* __restrict__ b4,
    const float* __restrict__ W5, const float* __restrict__ b5,
    float* __restrict__ out) {
  __shared__ float p_s[128], r1_s[256], r2_s[128];
  const int b = blockIdx.x, tid = threadIdx.x;
  if (tid < 128) p_s[tid] = pooled[b * 128 + tid];
  __syncthreads();
  {
    float acc = b3[tid];
#pragma unroll 8
    for (int k = 0; k < 128; ++k) acc = fmaf(p_s[k], W3[k * 256 + tid], acc);
    r1_s[tid] = fmaxf(acc, 0.f);
  }
  __syncthreads();
  if (tid < 128) {
    float acc = b4[tid];
#pragma unroll 8
    for (int k = 0; k < 256; ++k) acc = fmaf(r1_s[k], W4[k * 128 + tid], acc);
    r2_s[tid] = fmaxf(acc, 0.f);
  }
  __syncthreads();
  if (tid < 64) {
    float acc = b5[tid];
#pragma unroll 8
    for (int k = 0; k < 128; ++k) acc = fmaf(r2_s[k], W5[k * 64 + tid], acc);
    out[b * 64 + tid] = acc;
  }
}

extern "C" void kernel_launch(void* const* d_in, const int* in_sizes, int n_in,
                              void* d_out, int out_size, void* d_ws, size_t ws_size,
                              hipStream_t stream) {
  const float* dm      = (const float*)d_in[0];
  const int*   lengths = (const int*)d_in[1];
  const float* W1 = (const float*)d_in[2];
  const float* b1 = (const float*)d_in[3];
  const float* W2 = (const float*)d_in[4];
  const float* b2 = (const float*)d_in[5];
  const float* W3 = (const float*)d_in[6];
  const float* b3 = (const float*)d_in[7];
  const float* W4 = (const float*)d_in[8];
  const float* b4 = (const float*)d_in[9];
  const float* W5 = (const float*)d_in[10];
  const float* b5 = (const float*)d_in[11];

  float* ws = (float*)d_ws;
  float2* table2 = (float2*)ws;          // 2*65*64 float2 = 16640 floats
  float* tsort   = ws + 16640;           // 64
  float* pooled  = ws + 16704;           // 32*128 = 4096

  build_tables<<<SEGS, 128, 0, stream>>>(W1, b1, W2, b2, table2, tsort, pooled);
  phi_pool<<<dim3(16, 2, NB), 512, 0, stream>>>(dm, lengths, table2, tsort, pooled);
  rho_mlp<<<NB, 256, 0, stream>>>(pooled, W3, b3, W4, b4, W5, b5, (float*)d_out);
}